// Round 6
// baseline (6390.573 us; speedup 1.0000x reference)
//
#include <hip/hip_runtime.h>

#define TT 512
#define BB 256
#define HH 512
#define FH 2048   // 4*H

typedef __attribute__((ext_vector_type(8))) short short8;
typedef __attribute__((ext_vector_type(4))) short short4v;
typedef __attribute__((ext_vector_type(4))) float f32x4;

__device__ __forceinline__ short f2bf(float f) {
  union { float f; unsigned u; } v; v.f = f;
  unsigned r = v.u + 0x7fffu + ((v.u >> 16) & 1u);   // RNE
  return (short)(r >> 16);
}
__device__ __forceinline__ unsigned short f2h(float f) {
  union { _Float16 h; unsigned short u; } v;
  v.h = (_Float16)f;
  return v.u;
}
__device__ __forceinline__ float h2f(unsigned short u) {
  union { _Float16 h; unsigned short u; } v;
  v.u = u;
  return (float)v.h;
}

__device__ __forceinline__ float sigm(float x) {
  return 1.f / (1.f + __expf(-x));
}
__device__ __forceinline__ float tanh_fast(float x) {
  float e = __expf(2.f * x);
  return 1.f - 2.f / (e + 1.f);
}

// prep: weight transposes (bf16), X -> bf16, tagged h init, c init, fallback h init.
__global__ void prep_kernel(const float* __restrict__ Wi, const float* __restrict__ Wh,
                            const float* __restrict__ h0, const float* __restrict__ c0,
                            const float* __restrict__ x,
                            short* __restrict__ WiT, short* __restrict__ WhT,
                            unsigned long long* __restrict__ hb0,
                            unsigned long long* __restrict__ hb1,
                            float* __restrict__ cb, short* __restrict__ hbf,
                            short* __restrict__ Xb) {
  int idx = blockIdx.x * blockDim.x + threadIdx.x;
  int stride = gridDim.x * blockDim.x;
  for (int i = idx; i < FH * HH; i += stride) {
    int col = i >> 9;
    int k = i & 511;
    WiT[i] = f2bf(Wi[(size_t)k * FH + col]);
    WhT[i] = f2bf(Wh[(size_t)k * FH + col]);
  }
  for (int i = idx; i < BB * HH; i += stride) {
    hbf[i] = f2bf(h0[i]);
    cb[i] = c0[i];
  }
  // tagged h words: word i = (row i>>8, colpair i&255); hb0 = (tag 0, h0), hb1 = stale
  for (int i = idx; i < BB * 256; i += stride) {
    int row = i >> 8;
    int cpx = (i & 255) * 2;
    unsigned lo = (unsigned)(unsigned short)f2bf(h0[(size_t)row * HH + cpx]) |
                  ((unsigned)(unsigned short)f2bf(h0[(size_t)row * HH + cpx + 1]) << 16);
    hb0[i] = (unsigned long long)lo;               // tag 0
    hb1[i] = 0xFFFFFFFF00000000ull;                // tag -1 (stale for all t)
  }
  // X fp32 -> bf16
  const size_t nx4 = (size_t)TT * BB * HH / 4;
  for (size_t i = idx; i < nx4; i += stride) {
    f32x4 v = *(const f32x4*)(x + i * 4);
    short4v s = { f2bf(v[0]), f2bf(v[1]), f2bf(v[2]), f2bf(v[3]) };
    *(short4v*)(Xb + i * 4) = s;
  }
}

// Gx16[row][col] = fp16(Xb[rowBase+row][:] @ WiT[col][:] + bias[col]).
// grid (8 coltiles, rowtiles) — x fastest so the 8 col-tiles of one row-tile
// run adjacently and the X tile stays L2-hot.
__global__ __launch_bounds__(256) void precomp_kernel(
    const short* __restrict__ Xb, const short* __restrict__ WiT,
    const float* __restrict__ bias, unsigned short* __restrict__ Gx,
    int rowBase) {
  __shared__ short lx[32 * 520];
  const int tid = threadIdx.x;
  const int rb = blockIdx.y * 32;
  const size_t grow = (size_t)rowBase + rb;

#pragma unroll
  for (int e = tid * 8; e < 32 * 512; e += 2048) {
    int row = e >> 9;
    int col = e & 511;
    *(short8*)(&lx[row * 520 + col]) = *(const short8*)(Xb + (grow + row) * 512 + col);
  }
  __syncthreads();

  const int wid = tid >> 6;
  const int lane = tid & 63;
  const int lc = lane & 15;
  const int kg = lane >> 4;
  const int n0 = blockIdx.x * 256 + wid * 64;

  f32x4 acc[2][4] = {};
#pragma unroll
  for (int kk = 0; kk < 16; ++kk) {
    const int ko = kk * 32 + kg * 8;
    short8 a0 = *(const short8*)(&lx[lc * 520 + ko]);
    short8 a1 = *(const short8*)(&lx[(16 + lc) * 520 + ko]);
#pragma unroll
    for (int nf = 0; nf < 4; ++nf) {
      const short8 b = *(const short8*)(WiT + (size_t)(n0 + nf * 16 + lc) * 512 + ko);
      acc[0][nf] = __builtin_amdgcn_mfma_f32_16x16x32_bf16(a0, b, acc[0][nf], 0, 0, 0);
      acc[1][nf] = __builtin_amdgcn_mfma_f32_16x16x32_bf16(a1, b, acc[1][nf], 0, 0, 0);
    }
  }

  for (int nf = 0; nf < 4; ++nf) {
    int col = n0 + nf * 16 + lc;
    float bv = bias[col];
    for (int m = 0; m < 2; ++m)
      for (int j = 0; j < 4; ++j) {
        int row = rb + m * 16 + kg * 4 + j;
        Gx[(size_t)row * FH + col] = f2h(acc[m][nf][j] + bv);
      }
  }
}

// Persistent step kernel: 256 blocks = 8 groups x 32 col-groups, 256 threads.
// h exchanged as tagged u64 words (tag32 | 2xbf16): single-word atomicity makes
// tag+data arrive together -> no flags, no fences, ONE L3 round trip per step.
// Waves 0-1 compute (16 rows each, all 4 gates -> wave-local epilogue, no gex).
// One __syncthreads per step (ah double-buffered by parity).
__global__ __launch_bounds__(256) void lstm_persist(
    const int* __restrict__ resets,         // (T,B)
    const short* __restrict__ WhT,          // (2048,512) bf16 bits
    const unsigned short* __restrict__ Gx,  // (ct,B,2048) fp16, bias included
    unsigned long long* __restrict__ hb0,   // (B,256) tagged words, parity 0
    unsigned long long* __restrict__ hb1,   // parity 1
    float* __restrict__ cb,                 // (B,H) c state (chunk carry)
    float* __restrict__ out,                // output base
    int t0, int ct) {
  extern __shared__ char dynsm[];
  short* whs = (short*)dynsm;                  // 64 gate-cols x 512 k, swizzled, 64 KB
  __shared__ short ah[2][32 * 512];            // double-buffered h tile, swizzled, 64 KB

  const int tid = threadIdx.x;
  const int bid = blockIdx.x;
  const int grp = bid >> 5;
  const int j = bid & 31;
  const int rb = grp * 32;
  const int hc0 = j * 16;

  const int wid = tid >> 6;
  const int lane = tid & 63;
  const int lc = lane & 15;
  const int kg = lane >> 4;

  // ---- Wh slice -> LDS (once, swizzled) ----
  {
    const int lcol = tid >> 2;            // 0..63 gate-col
    const int part = tid & 3;             // 128-short quarters
    const int g = lcol >> 4;
    const int gcol = g * 512 + hc0 + (lcol & 15);
    const short* src = WhT + (size_t)gcol * 512 + part * 128;
    const int dbase = lcol * 1024 + part * 256;
    const int sw = (lcol & 7) << 4;
#pragma unroll
    for (int it = 0; it < 16; ++it) {
      short8 v = *(const short8*)(src + it * 8);
      *(short8*)((char*)whs + ((dbase + it * 16) ^ sw)) = v;
    }
  }

  // compute waves 0-1: wave owns rows [wid*16, wid*16+16); thread rows rwb+jj
  const int rwb = wid * 16 + kg * 4;
  float creg[4] = {0.f, 0.f, 0.f, 0.f};
  if (wid < 2) {
#pragma unroll
    for (int jj = 0; jj < 4; ++jj)
      creg[jj] = cb[(size_t)(rb + rwb + jj) * HH + hc0 + lc];
  }

  __syncthreads();

  for (int t = t0; t < t0 + ct; ++t) {
    const int p = t & 1;

    // ---- Gx + reset prefetch (compute waves; latency hides under poll/MFMA) ----
    unsigned gx8[8];
    int rstE[4];
    if (wid < 2) {
      const unsigned short* gxb = Gx + (size_t)(t - t0) * BB * FH;
#pragma unroll
      for (int g = 0; g < 4; ++g)
#pragma unroll
        for (int rr = 0; rr < 2; ++rr) {
          int row = rb + wid * 16 + kg * 4 + (lc & 1) * 2 + rr;
          gx8[g * 2 + rr] =
              *(const unsigned*)(gxb + (size_t)row * FH + g * 512 + hc0 + (lc & ~1));
        }
#pragma unroll
      for (int jj = 0; jj < 4; ++jj)
        rstE[jj] = resets[(size_t)t * BB + rb + rwb + jj];
    }

    // ---- poll + stage h(t) into ah[p] (all 256 threads; colpair = tid) ----
    {
      const unsigned long long* hsrc = (p ? hb1 : hb0) + (size_t)rb * 256 + tid;
      unsigned long long v[32];
#pragma unroll
      for (int it = 0; it < 32; ++it)
        v[it] = __hip_atomic_load(&hsrc[it * 256], __ATOMIC_RELAXED,
                                  __HIP_MEMORY_SCOPE_AGENT);
      while (true) {
        bool ok = true;
#pragma unroll
        for (int it = 0; it < 32; ++it)
          ok &= ((unsigned)(v[it] >> 32) == (unsigned)t);
        if (ok) break;
#pragma unroll
        for (int it = 0; it < 32; ++it)
          if ((unsigned)(v[it] >> 32) != (unsigned)t)
            v[it] = __hip_atomic_load(&hsrc[it * 256], __ATOMIC_RELAXED,
                                      __HIP_MEMORY_SCOPE_AGENT);
      }
      char* ahp = (char*)ah[p];
#pragma unroll
      for (int it = 0; it < 32; ++it) {
        unsigned hw = (resets[(size_t)t * BB + rb + it] != 0) ? 0u : (unsigned)v[it];
        *(unsigned*)(ahp + ((it * 1024 + tid * 4) ^ ((it & 7) << 4))) = hw;
      }
    }
    __syncthreads();   // ah[p] ready; prior-step readers of ah[p^1] already done

    if (wid < 2) {
      // ---- MFMA: this wave's 16 rows x 16 h-cols x 4 gates, K=512 ----
      const char* ahp = (const char*)ah[p];
      const char* whb = (const char*)whs;
      const int sw = (lc & 7) << 4;
      f32x4 acc[4] = {};
#pragma unroll
      for (int kk = 0; kk < 16; ++kk) {
        const int kb = kk * 64 + kg * 16;
        short8 a = *(const short8*)(ahp + (((wid * 16 + lc) * 1024 + kb) ^ sw));
#pragma unroll
        for (int g = 0; g < 4; ++g) {
          short8 b = *(const short8*)(whb + (((g * 16 + lc) * 1024 + kb) ^ sw));
          acc[g] = __builtin_amdgcn_mfma_f32_16x16x32_bf16(a, b, acc[g], 0, 0, 0);
        }
      }

      // ---- decode Gx: mine = rows (lc&1)*2+{0,1}; partner has the other pair ----
      float garr[4][4];
#pragma unroll
      for (int g = 0; g < 4; ++g)
#pragma unroll
        for (int rr = 0; rr < 2; ++rr) {
          unsigned mine = gx8[g * 2 + rr];
          unsigned part = (unsigned)__shfl_xor((int)mine, 1, 64);
          int myoff = (lc & 1) * 2;
          float mv = h2f((unsigned short)((lc & 1) ? (mine >> 16) : (mine & 0xffffu)));
          float pv = h2f((unsigned short)((lc & 1) ? (part >> 16) : (part & 0xffffu)));
          garr[g][myoff + rr] = mv;
          garr[g][(2 - myoff) + rr] = pv;
        }

      // ---- cell update ----
      float hn[4];
#pragma unroll
      for (int jj = 0; jj < 4; ++jj) {
        float gi = acc[0][jj] + garr[0][jj];
        float gf = acc[1][jj] + garr[1][jj];
        float gg = acc[2][jj] + garr[2][jj];
        float go = acc[3][jj] + garr[3][jj];
        float cold = rstE[jj] ? 0.f : creg[jj];
        float cn = sigm(gf) * cold + sigm(gi) * tanh_fast(gg);
        hn[jj] = sigm(go) * tanh_fast(cn);
        creg[jj] = cn;
      }

      // ---- publish tagged h words (fire-and-forget; no fence, no flag) ----
      float ph[4];
#pragma unroll
      for (int jj = 0; jj < 4; ++jj) ph[jj] = __shfl_xor(hn[jj], 1, 64);
      unsigned long long* hdst = ((t + 1) & 1) ? hb1 : hb0;
      const unsigned long long tagp = ((unsigned long long)(unsigned)(t + 1)) << 32;
#pragma unroll
      for (int s = 0; s < 2; ++s) {
        const int jj = (lc & 1) * 2 + s;
        unsigned lo16 = (unsigned)(unsigned short)f2bf((lc & 1) ? ph[jj] : hn[jj]);
        unsigned hi16 = (unsigned)(unsigned short)f2bf((lc & 1) ? hn[jj] : ph[jj]);
        unsigned long long w = tagp | (unsigned long long)(lo16 | (hi16 << 16));
        size_t widx = (size_t)(rb + rwb + jj) * 256 + (hc0 >> 1) + (lc >> 1);
        __hip_atomic_store(&hdst[widx], w, __ATOMIC_RELAXED,
                           __HIP_MEMORY_SCOPE_AGENT);
      }

      // ---- ys / finals: off the critical path ----
      float* ysrow = out + (size_t)t * BB * HH;
#pragma unroll
      for (int jj = 0; jj < 4; ++jj)
        ysrow[(size_t)(rb + rwb + jj) * HH + hc0 + lc] = hn[jj];
      if (t == TT - 1) {
#pragma unroll
        for (int jj = 0; jj < 4; ++jj) {
          size_t gidx = (size_t)(rb + rwb + jj) * HH + hc0 + lc;
          out[(size_t)TT * BB * HH + gidx] = creg[jj];
          out[(size_t)TT * BB * HH + (size_t)BB * HH + gidx] = hn[jj];
        }
      }
    }
  }

  // carry c to next chunk
  if (wid < 2) {
#pragma unroll
    for (int jj = 0; jj < 4; ++jj)
      cb[(size_t)(rb + rwb + jj) * HH + hc0 + lc] = creg[jj];
  }
}

// ---- fallback path (tiny ws): full-K per-step kernel ----
__global__ __launch_bounds__(64) void lstm_step_fullk(
    const float* __restrict__ xt, const int* __restrict__ rst,
    const float* __restrict__ bias, const short* __restrict__ WiT,
    const short* __restrict__ WhT, const short* __restrict__ hin,
    short* __restrict__ hout, float* __restrict__ cbuf, float* __restrict__ ys) {
  const int lane = threadIdx.x;
  const int lc = lane & 15;
  const int kg = lane >> 4;
  const int r0 = blockIdx.x * 16;
  const int h0 = blockIdx.y * 16;
  const int hc = h0 + lc;

  float coldv[4];
  int rstj[4];
#pragma unroll
  for (int jj = 0; jj < 4; ++jj) {
    int row = r0 + kg * 4 + jj;
    rstj[jj] = rst[row];
    coldv[jj] = cbuf[(size_t)row * HH + hc];
  }

  const int rowA = r0 + lc;
  const bool rm = rst[rowA] != 0;
  const short8 zero = {};
  f32x4 acc[4] = {};
#pragma unroll
  for (int kk = 0; kk < 16; ++kk) {
    const int ko = kk * 32 + kg * 8;
    f32x4 u0 = *(const f32x4*)(xt + (size_t)rowA * HH + ko);
    f32x4 u1 = *(const f32x4*)(xt + (size_t)rowA * HH + ko + 4);
    short8 a;
#pragma unroll
    for (int e = 0; e < 4; ++e) { a[e] = f2bf(u0[e]); a[e + 4] = f2bf(u1[e]); }
#pragma unroll
    for (int g = 0; g < 4; ++g) {
      const short8 b = *(const short8*)(WiT + (size_t)(g * HH + h0 + lc) * HH + ko);
      acc[g] = __builtin_amdgcn_mfma_f32_16x16x32_bf16(a, b, acc[g], 0, 0, 0);
    }
  }
#pragma unroll
  for (int kk = 0; kk < 16; ++kk) {
    const int ko = kk * 32 + kg * 8;
    short8 a = rm ? zero : *(const short8*)(hin + (size_t)rowA * HH + ko);
#pragma unroll
    for (int g = 0; g < 4; ++g) {
      const short8 b = *(const short8*)(WhT + (size_t)(g * HH + h0 + lc) * HH + ko);
      acc[g] = __builtin_amdgcn_mfma_f32_16x16x32_bf16(a, b, acc[g], 0, 0, 0);
    }
  }

#pragma unroll
  for (int jj = 0; jj < 4; ++jj) {
    int row = r0 + kg * 4 + jj;
    float gi = acc[0][jj] + bias[0 * HH + hc];
    float gf = acc[1][jj] + bias[1 * HH + hc];
    float gg = acc[2][jj] + bias[2 * HH + hc];
    float go = acc[3][jj] + bias[3 * HH + hc];
    float cold = rstj[jj] ? 0.f : coldv[jj];
    float cn = sigm(gf) * cold + sigm(gi) * tanh_fast(gg);
    float hn = sigm(go) * tanh_fast(cn);
    cbuf[(size_t)row * HH + hc] = cn;
    hout[(size_t)row * HH + hc] = f2bf(hn);
    ys[(size_t)row * HH + hc] = hn;
  }
}

__global__ void finalize_kernel(const float* __restrict__ cbuf, float* __restrict__ out) {
  int i = blockIdx.x * blockDim.x + threadIdx.x;
  if (i < BB * HH) {
    size_t base = (size_t)TT * BB * HH;
    out[base + i] = cbuf[i];
    out[base + BB * HH + i] = out[(size_t)(TT - 1) * BB * HH + i];
  }
}

extern "C" void kernel_launch(void* const* d_in, const int* in_sizes, int n_in,
                              void* d_out, int out_size, void* d_ws, size_t ws_size,
                              hipStream_t stream) {
  const float* x      = (const float*)d_in[0];
  const int*   resets = (const int*)d_in[1];
  const float* c0     = (const float*)d_in[2];
  const float* h0     = (const float*)d_in[3];
  const float* Wi     = (const float*)d_in[4];
  const float* Wh     = (const float*)d_in[5];
  const float* bias   = (const float*)d_in[6];
  float* out = (float*)d_out;

  char* ws = (char*)d_ws;
  short* WiT = (short*)ws;                                        // 2 MiB
  short* WhT = (short*)(ws + (2u << 20));                         // 2 MiB
  unsigned long long* hb0 = (unsigned long long*)(ws + (4u << 20));        // 512 KiB
  unsigned long long* hb1 = (unsigned long long*)(ws + (4u << 20) + (512u << 10)); // 512 KiB
  float* cb  = (float*)(ws + (5u << 20));                         // 512 KiB
  short* hbf0 = (short*)(ws + (5u << 20) + (512u << 10));         // 256 KiB (fallback)
  short* hbf1 = hbf0 + BB * HH;                                   // 256 KiB (fallback)
  short* Xb  = (short*)(ws + (6u << 20));                         // 128 MiB
  const size_t GX_OFF = (6u << 20) + (size_t)TT * BB * HH * 2;    // 134 MiB
  unsigned short* Gx = (unsigned short*)(ws + GX_OFF);

  const size_t perT = (size_t)BB * FH * 2;                        // 1 MiB/step fp16
  int chunkT = 0;
  if (ws_size > GX_OFF + perT) chunkT = (int)((ws_size - GX_OFF) / perT);
  if (chunkT > TT) chunkT = TT;

  prep_kernel<<<2048, 256, 0, stream>>>(Wi, Wh, h0, c0, x, WiT, WhT,
                                        hb0, hb1, cb, hbf0, Xb);

  if (chunkT >= 1) {
    for (int t0 = 0; t0 < TT; t0 += chunkT) {
      int ct = (TT - t0 < chunkT) ? (TT - t0) : chunkT;
      precomp_kernel<<<dim3(8, ct * 8), 256, 0, stream>>>(Xb, WiT, bias, Gx, t0 * BB);
      lstm_persist<<<256, 256, 65536, stream>>>(resets, WhT, Gx, hb0, hb1,
                                                cb, out, t0, ct);
    }
  } else {
    for (int t = 0; t < TT; ++t) {
      const short* hin = (t & 1) ? hbf1 : hbf0;
      short* hout      = (t & 1) ? hbf0 : hbf1;
      lstm_step_fullk<<<dim3(16, 32), 64, 0, stream>>>(
          x + (size_t)t * BB * HH, resets + (size_t)t * BB, bias, WiT, WhT,
          hin, hout, cb, out + (size_t)t * BB * HH);
    }
    finalize_kernel<<<(BB * HH + 255) / 256, 256, 0, stream>>>(cb, out);
  }
}

// Round 7
// 2546.047 us; speedup vs baseline: 2.5100x; 2.5100x over previous
//
#include <hip/hip_runtime.h>

#define TT 512
#define BB 256
#define HH 512
#define FH 2048   // 4*H

typedef __attribute__((ext_vector_type(8))) short short8;
typedef __attribute__((ext_vector_type(4))) short short4v;
typedef __attribute__((ext_vector_type(4))) float f32x4;
typedef __attribute__((ext_vector_type(2))) float f32x2;

__device__ __forceinline__ short f2bf(float f) {
  union { float f; unsigned u; } v; v.f = f;
  unsigned r = v.u + 0x7fffu + ((v.u >> 16) & 1u);   // RNE
  return (short)(r >> 16);
}
__device__ __forceinline__ unsigned short f2h(float f) {
  union { _Float16 h; unsigned short u; } v;
  v.h = (_Float16)f;
  return v.u;
}
__device__ __forceinline__ float h2f(unsigned short u) {
  union { _Float16 h; unsigned short u; } v;
  v.u = u;
  return (float)v.h;
}

__device__ __forceinline__ float sigm(float x) {
  return 1.f / (1.f + __expf(-x));
}
__device__ __forceinline__ float tanh_fast(float x) {
  float e = __expf(2.f * x);
  return 1.f - 2.f / (e + 1.f);
}

// prep: weight transposes (bf16), X -> bf16, packed h init, c init, flags, fallback h.
__global__ void prep_kernel(const float* __restrict__ Wi, const float* __restrict__ Wh,
                            const float* __restrict__ h0, const float* __restrict__ c0,
                            const float* __restrict__ x,
                            short* __restrict__ WiT, short* __restrict__ WhT,
                            unsigned* __restrict__ hb0, float* __restrict__ cb,
                            short* __restrict__ hbf, short* __restrict__ Xb,
                            int* __restrict__ done) {
  int idx = blockIdx.x * blockDim.x + threadIdx.x;
  int stride = gridDim.x * blockDim.x;
  for (int i = idx; i < FH * HH; i += stride) {
    int col = i >> 9;
    int k = i & 511;
    WiT[i] = f2bf(Wi[(size_t)k * FH + col]);
    WhT[i] = f2bf(Wh[(size_t)k * FH + col]);
  }
  for (int i = idx; i < BB * HH; i += stride) {
    hbf[i] = f2bf(h0[i]);
    cb[i] = c0[i];
  }
  // packed h pairs for persist path, parity-0 buffer
  for (int i = idx; i < BB * 256; i += stride) {
    int row = i >> 8;
    int cpx = (i & 255) * 2;
    hb0[i] = (unsigned)(unsigned short)f2bf(h0[(size_t)row * HH + cpx]) |
             ((unsigned)(unsigned short)f2bf(h0[(size_t)row * HH + cpx + 1]) << 16);
  }
  for (int i = idx; i < 8 * TT * 32; i += stride) done[i] = 0;
  // X fp32 -> bf16
  const size_t nx4 = (size_t)TT * BB * HH / 4;
  for (size_t i = idx; i < nx4; i += stride) {
    f32x4 v = *(const f32x4*)(x + i * 4);
    short4v s = { f2bf(v[0]), f2bf(v[1]), f2bf(v[2]), f2bf(v[3]) };
    *(short4v*)(Xb + i * 4) = s;
  }
}

// 128x128-tile GEMM: Gx16 = fp16(Xb @ WiT^T + bias). 4 waves, BK=64,
// reg-staged XOR-swizzled LDS. Grid (16 coltiles, rowtiles) - coltile fastest.
__global__ __launch_bounds__(256) void precomp_kernel(
    const short* __restrict__ Xb, const short* __restrict__ WiT,
    const float* __restrict__ bias, unsigned short* __restrict__ Gx,
    int rowBase) {
  __shared__ short As[128 * 64];
  __shared__ short Bs[128 * 64];

  const int tid = threadIdx.x;
  const int cb0 = blockIdx.x * 128;
  const int rb = blockIdx.y * 128;          // chunk-relative row base
  const size_t grow = (size_t)rowBase + rb; // absolute Xb row base

  const int wid = tid >> 6;
  const int lane = tid & 63;
  const int lc = lane & 15;
  const int kg = lane >> 4;
  const int wm = wid >> 1;                  // 0..1 row-half
  const int wn = wid & 1;                   // 0..1 col-half
  const int m0 = wm * 64;
  const int n0 = wn * 64;

  f32x4 acc[4][4] = {};

  for (int kt = 0; kt < 8; ++kt) {
    const int k0 = kt * 64;
    __syncthreads();   // prior iteration's reads complete
#pragma unroll
    for (int i = 0; i < 4; ++i) {
      const int idx = tid * 4 + i;
      const int row = idx >> 3;
      const int kc = idx & 7;
      short8 av = *(const short8*)(Xb + (grow + row) * 512 + k0 + kc * 8);
      short8 bv = *(const short8*)(WiT + (size_t)(cb0 + row) * 512 + k0 + kc * 8);
      const int off = (row * 128 + kc * 16) ^ ((row & 7) << 4);
      *(short8*)((char*)As + off) = av;
      *(short8*)((char*)Bs + off) = bv;
    }
    __syncthreads();

    const int sw = (lc & 7) << 4;
#pragma unroll
    for (int ks = 0; ks < 2; ++ks) {
      const int kb = ks * 64 + kg * 16;
      short8 af[4], bf[4];
#pragma unroll
      for (int m = 0; m < 4; ++m)
        af[m] = *(const short8*)((char*)As + (((m0 + m * 16 + lc) * 128 + kb) ^ sw));
#pragma unroll
      for (int n = 0; n < 4; ++n)
        bf[n] = *(const short8*)((char*)Bs + (((n0 + n * 16 + lc) * 128 + kb) ^ sw));
#pragma unroll
      for (int m = 0; m < 4; ++m)
#pragma unroll
        for (int n = 0; n < 4; ++n)
          acc[m][n] = __builtin_amdgcn_mfma_f32_16x16x32_bf16(af[m], bf[n],
                                                              acc[m][n], 0, 0, 0);
    }
  }

  // epilogue: C row = rb + m0 + m*16 + kg*4 + j (chunk-relative), col = cb0+n0+n*16+lc
#pragma unroll
  for (int n = 0; n < 4; ++n) {
    const int col = cb0 + n0 + n * 16 + lc;
    const float bv = bias[col];
#pragma unroll
    for (int m = 0; m < 4; ++m) {
      const int rloc = rb + m0 + m * 16 + kg * 4;
#pragma unroll
      for (int j = 0; j < 4; ++j)
        Gx[(size_t)(rloc + j) * FH + col] = f2h(acc[m][n][j] + bv);
    }
  }
}

// Persistent step kernel (R4 structure): 256 blocks = 8 groups x 32 col-groups.
// h exchanged via relaxed agent-scope atomics (L3); flag per block per step;
// wave-0 poll with s_sleep backoff; ys/finals stored AFTER the flag publish.
__global__ __launch_bounds__(256) void lstm_persist(
    const int* __restrict__ resets,         // (T,B)
    const short* __restrict__ WhT,          // (2048,512) bf16 bits
    const unsigned short* __restrict__ Gx,  // (ct,B,2048) fp16, bias included
    unsigned* __restrict__ hbA,             // (B,256) u32 bf16-pairs, parity 0
    unsigned* __restrict__ hbB,             // parity 1
    float* __restrict__ cb,                 // (B,H) c state (chunk carry)
    float* __restrict__ out,                // output base
    int* __restrict__ done,                 // (8,T,32) flags
    int t0, int ct) {
  extern __shared__ short whs[];          // 64 gate-cols x 512 k, swizzled (64 KB)
  __shared__ short ah[32 * 512];          // 32 rows x 512 k, swizzled (32 KB)
  __shared__ float gex[4 * 32 * 17];      // gate exchange (8.5 KB)

  const int tid = threadIdx.x;
  const int bid = blockIdx.x;
  const int grp = bid >> 5;          // batch group 0..7
  const int j = bid & 31;            // col group
  const int rb = grp * 32;
  const int hc0 = j * 16;

  const int wid = tid >> 6;
  const int lane = tid & 63;
  const int lc = lane & 15;
  const int kg = lane >> 4;

  // ---- Wh slice -> LDS (once, swizzled) ----
  {
    const int lcol = tid >> 2;            // 0..63 gate-col
    const int part = tid & 3;             // 128-short quarters
    const int g = lcol >> 4;
    const int gcol = g * 512 + hc0 + (lcol & 15);
    const short* src = WhT + (size_t)gcol * 512 + part * 128;
    const int dbase = lcol * 1024 + part * 256;
    const int sw = (lcol & 7) << 4;
#pragma unroll
    for (int it = 0; it < 16; ++it) {
      short8 v = *(const short8*)(src + it * 8);
      *(short8*)((char*)whs + ((dbase + it * 16) ^ sw)) = v;
    }
  }

  // ---- epilogue ownership: row = tid>>3 (0..31), col pair cp = (tid&7)*2 ----
  const int erow = tid >> 3;
  const int cp = (tid & 7) * 2;
  float creg[2];
  {
    const float* cs = cb + (size_t)(rb + erow) * HH + hc0 + cp;
    creg[0] = cs[0];
    creg[1] = cs[1];
  }

  __syncthreads();

  for (int t = t0; t < t0 + ct; ++t) {
    // ---- prefetch Gx (fp16 pairs) + resets; no dependency on the barrier ----
    const unsigned short* gxb =
        Gx + ((size_t)(t - t0) * BB + (rb + erow)) * FH + hc0 + cp;
    unsigned gxu[4];
#pragma unroll
    for (int g = 0; g < 4; ++g) gxu[g] = *(const unsigned*)(gxb + g * 512);
    const int* rstT = resets + (size_t)t * BB;
    const int rstE = rstT[rb + erow];

    // ---- group barrier: wait until all 32 producer blocks published t-1 ----
    if (t > t0) {
      if (wid == 0) {
        int* dn = done + ((size_t)grp * TT + (t - 1)) * 32;
        bool ok;
        do {
          int v = (lane < 32)
                      ? __hip_atomic_load(&dn[lane], __ATOMIC_RELAXED,
                                          __HIP_MEMORY_SCOPE_AGENT)
                      : 1;
          ok = __all(v != 0);
          if (!ok) __builtin_amdgcn_s_sleep(2);
        } while (!ok);
      }
      __syncthreads();
    }

    // ---- stage h: batched relaxed L3 loads -> swizzled LDS ----
    {
      unsigned* hsrc = ((t & 1) ? hbB : hbA) + (size_t)rb * 256;
      unsigned hv[32];
#pragma unroll
      for (int it = 0; it < 32; ++it)
        hv[it] = __hip_atomic_load(&hsrc[it * 256 + tid], __ATOMIC_RELAXED,
                                   __HIP_MEMORY_SCOPE_AGENT);
#pragma unroll
      for (int it = 0; it < 32; ++it) {
        unsigned v = (rstT[rb + it] != 0) ? 0u : hv[it];
        *(unsigned*)((char*)ah + ((it * 1024 + tid * 4) ^ ((it & 7) << 4))) = v;
      }
    }
    __syncthreads();

    // ---- MFMA: waves 0,1 each compute 2 gates x 2 row-frags ----
    if (wid < 2) {
      const int sw = (lc & 7) << 4;
      f32x4 acc[2][2] = {};
#pragma unroll
      for (int kk = 0; kk < 16; ++kk) {
        const int kb = kk * 64 + kg * 16;
        short8 a0 = *(const short8*)((char*)ah + ((lc * 1024 + kb) ^ sw));
        short8 a1 = *(const short8*)((char*)ah + (((lc + 16) * 1024 + kb) ^ sw));
        short8 b0 = *(const short8*)((char*)whs +
                      ((((wid * 2 + 0) * 16 + lc) * 1024 + kb) ^ sw));
        short8 b1 = *(const short8*)((char*)whs +
                      ((((wid * 2 + 1) * 16 + lc) * 1024 + kb) ^ sw));
        acc[0][0] = __builtin_amdgcn_mfma_f32_16x16x32_bf16(a0, b0, acc[0][0], 0, 0, 0);
        acc[0][1] = __builtin_amdgcn_mfma_f32_16x16x32_bf16(a1, b0, acc[0][1], 0, 0, 0);
        acc[1][0] = __builtin_amdgcn_mfma_f32_16x16x32_bf16(a0, b1, acc[1][0], 0, 0, 0);
        acc[1][1] = __builtin_amdgcn_mfma_f32_16x16x32_bf16(a1, b1, acc[1][1], 0, 0, 0);
      }
#pragma unroll
      for (int gs = 0; gs < 2; ++gs)
#pragma unroll
        for (int m = 0; m < 2; ++m)
#pragma unroll
          for (int jj = 0; jj < 4; ++jj)
            gex[(wid * 2 + gs) * 544 + (m * 16 + kg * 4 + jj) * 17 + lc] =
                acc[gs][m][jj];
    }
    __syncthreads();

    // ---- epilogue: thread owns (erow, cols cp, cp+1) ----
    {
      unsigned* hdst = (t & 1) ? hbA : hbB;
      const int gb = erow * 17 + cp;
      float gi0 = gex[0 * 544 + gb] + h2f((unsigned short)(gxu[0] & 0xffffu));
      float gi1 = gex[0 * 544 + gb + 1] + h2f((unsigned short)(gxu[0] >> 16));
      float gf0 = gex[1 * 544 + gb] + h2f((unsigned short)(gxu[1] & 0xffffu));
      float gf1 = gex[1 * 544 + gb + 1] + h2f((unsigned short)(gxu[1] >> 16));
      float gg0 = gex[2 * 544 + gb] + h2f((unsigned short)(gxu[2] & 0xffffu));
      float gg1 = gex[2 * 544 + gb + 1] + h2f((unsigned short)(gxu[2] >> 16));
      float go0 = gex[3 * 544 + gb] + h2f((unsigned short)(gxu[3] & 0xffffu));
      float go1 = gex[3 * 544 + gb + 1] + h2f((unsigned short)(gxu[3] >> 16));
      float cold0 = rstE ? 0.f : creg[0];
      float cold1 = rstE ? 0.f : creg[1];
      float cn0 = sigm(gf0) * cold0 + sigm(gi0) * tanh_fast(gg0);
      float cn1 = sigm(gf1) * cold1 + sigm(gi1) * tanh_fast(gg1);
      float hn0 = sigm(go0) * tanh_fast(cn0);
      float hn1 = sigm(go1) * tanh_fast(cn1);
      creg[0] = cn0;
      creg[1] = cn1;
      unsigned pack = (unsigned)(unsigned short)f2bf(hn0) |
                      ((unsigned)(unsigned short)f2bf(hn1) << 16);
      __hip_atomic_store(&hdst[(size_t)(rb + erow) * 256 + (hc0 >> 1) + (tid & 7)],
                         pack, __ATOMIC_RELAXED, __HIP_MEMORY_SCOPE_AGENT);
      asm volatile("s_waitcnt vmcnt(0)" ::: "memory");  // h store acked (this thread)
      __syncthreads();                                  // all threads' h stores done
      if (tid == 0)
        __hip_atomic_store(&done[((size_t)grp * TT + t) * 32 + j], 1,
                           __ATOMIC_RELAXED, __HIP_MEMORY_SCOPE_AGENT);
      // ys / finals AFTER the flag: off the critical path
      size_t gidx = (size_t)(rb + erow) * HH + hc0 + cp;
      *(f32x2*)(out + (size_t)t * BB * HH + gidx) = (f32x2){hn0, hn1};
      if (t == TT - 1) {
        out[(size_t)TT * BB * HH + gidx] = cn0;
        out[(size_t)TT * BB * HH + gidx + 1] = cn1;
        out[(size_t)TT * BB * HH + (size_t)BB * HH + gidx] = hn0;
        out[(size_t)TT * BB * HH + (size_t)BB * HH + gidx + 1] = hn1;
      }
    }
  }

  // carry c to next chunk
  {
    float* cs = cb + (size_t)(rb + erow) * HH + hc0 + cp;
    cs[0] = creg[0];
    cs[1] = creg[1];
  }
}

// ---- fallback path (tiny ws): full-K per-step kernel ----
__global__ __launch_bounds__(64) void lstm_step_fullk(
    const float* __restrict__ xt, const int* __restrict__ rst,
    const float* __restrict__ bias, const short* __restrict__ WiT,
    const short* __restrict__ WhT, const short* __restrict__ hin,
    short* __restrict__ hout, float* __restrict__ cbuf, float* __restrict__ ys) {
  const int lane = threadIdx.x;
  const int lc = lane & 15;
  const int kg = lane >> 4;
  const int r0 = blockIdx.x * 16;
  const int h0 = blockIdx.y * 16;
  const int hc = h0 + lc;

  float coldv[4];
  int rstj[4];
#pragma unroll
  for (int jj = 0; jj < 4; ++jj) {
    int row = r0 + kg * 4 + jj;
    rstj[jj] = rst[row];
    coldv[jj] = cbuf[(size_t)row * HH + hc];
  }

  const int rowA = r0 + lc;
  const bool rm = rst[rowA] != 0;
  const short8 zero = {};
  f32x4 acc[4] = {};
#pragma unroll
  for (int kk = 0; kk < 16; ++kk) {
    const int ko = kk * 32 + kg * 8;
    f32x4 u0 = *(const f32x4*)(xt + (size_t)rowA * HH + ko);
    f32x4 u1 = *(const f32x4*)(xt + (size_t)rowA * HH + ko + 4);
    short8 a;
#pragma unroll
    for (int e = 0; e < 4; ++e) { a[e] = f2bf(u0[e]); a[e + 4] = f2bf(u1[e]); }
#pragma unroll
    for (int g = 0; g < 4; ++g) {
      const short8 b = *(const short8*)(WiT + (size_t)(g * HH + h0 + lc) * HH + ko);
      acc[g] = __builtin_amdgcn_mfma_f32_16x16x32_bf16(a, b, acc[g], 0, 0, 0);
    }
  }
#pragma unroll
  for (int kk = 0; kk < 16; ++kk) {
    const int ko = kk * 32 + kg * 8;
    short8 a = rm ? zero : *(const short8*)(hin + (size_t)rowA * HH + ko);
#pragma unroll
    for (int g = 0; g < 4; ++g) {
      const short8 b = *(const short8*)(WhT + (size_t)(g * HH + h0 + lc) * HH + ko);
      acc[g] = __builtin_amdgcn_mfma_f32_16x16x32_bf16(a, b, acc[g], 0, 0, 0);
    }
  }

#pragma unroll
  for (int jj = 0; jj < 4; ++jj) {
    int row = r0 + kg * 4 + jj;
    float gi = acc[0][jj] + bias[0 * HH + hc];
    float gf = acc[1][jj] + bias[1 * HH + hc];
    float gg = acc[2][jj] + bias[2 * HH + hc];
    float go = acc[3][jj] + bias[3 * HH + hc];
    float cold = rstj[jj] ? 0.f : coldv[jj];
    float cn = sigm(gf) * cold + sigm(gi) * tanh_fast(gg);
    float hn = sigm(go) * tanh_fast(cn);
    cbuf[(size_t)row * HH + hc] = cn;
    hout[(size_t)row * HH + hc] = f2bf(hn);
    ys[(size_t)row * HH + hc] = hn;
  }
}

__global__ void finalize_kernel(const float* __restrict__ cbuf, float* __restrict__ out) {
  int i = blockIdx.x * blockDim.x + threadIdx.x;
  if (i < BB * HH) {
    size_t base = (size_t)TT * BB * HH;
    out[base + i] = cbuf[i];
    out[base + BB * HH + i] = out[(size_t)(TT - 1) * BB * HH + i];
  }
}

extern "C" void kernel_launch(void* const* d_in, const int* in_sizes, int n_in,
                              void* d_out, int out_size, void* d_ws, size_t ws_size,
                              hipStream_t stream) {
  const float* x      = (const float*)d_in[0];
  const int*   resets = (const int*)d_in[1];
  const float* c0     = (const float*)d_in[2];
  const float* h0     = (const float*)d_in[3];
  const float* Wi     = (const float*)d_in[4];
  const float* Wh     = (const float*)d_in[5];
  const float* bias   = (const float*)d_in[6];
  float* out = (float*)d_out;

  char* ws = (char*)d_ws;
  short* WiT = (short*)ws;                                         // 2 MiB
  short* WhT = (short*)(ws + (2u << 20));                          // 2 MiB
  unsigned* hb0 = (unsigned*)(ws + (4u << 20));                    // 256 KiB
  unsigned* hb1 = (unsigned*)(ws + (4u << 20) + (256u << 10));     // 256 KiB
  float* cb  = (float*)(ws + (4u << 20) + (512u << 10));           // 512 KiB
  short* hbf0 = (short*)(ws + (5u << 20));                         // 256 KiB (fallback)
  short* hbf1 = hbf0 + BB * HH;                                    // 256 KiB (fallback)
  int*   dn  = (int*)(ws + (5u << 20) + (512u << 10));             // 512 KiB flags
  short* Xb  = (short*)(ws + (6u << 20));                          // 128 MiB
  const size_t GX_OFF = (6u << 20) + (size_t)TT * BB * HH * 2;     // 134 MiB
  unsigned short* Gx = (unsigned short*)(ws + GX_OFF);

  const size_t perT = (size_t)BB * FH * 2;                         // 1 MiB/step fp16
  int chunkT = 0;
  if (ws_size > GX_OFF + perT) chunkT = (int)((ws_size - GX_OFF) / perT);
  if (chunkT > TT) chunkT = TT;
  chunkT &= ~1;   // keep chunks even so h-buffer parity stays aligned

  prep_kernel<<<2048, 256, 0, stream>>>(Wi, Wh, h0, c0, x, WiT, WhT,
                                        hb0, cb, hbf0, Xb, dn);

  if (chunkT >= 2) {
    for (int t0 = 0; t0 < TT; t0 += chunkT) {
      int ct = (TT - t0 < chunkT) ? (TT - t0) : chunkT;
      precomp_kernel<<<dim3(16, ct * 2), 256, 0, stream>>>(Xb, WiT, bias, Gx, t0 * BB);
      lstm_persist<<<256, 256, 65536, stream>>>(resets, WhT, Gx, hb0, hb1,
                                                cb, out, dn, t0, ct);
    }
  } else {
    for (int t = 0; t < TT; ++t) {
      const short* hin = (t & 1) ? hbf1 : hbf0;
      short* hout      = (t & 1) ? hbf0 : hbf1;
      lstm_step_fullk<<<dim3(16, 32), 64, 0, stream>>>(
          x + (size_t)t * BB * HH, resets + (size_t)t * BB, bias, WiT, WhT,
          hin, hout, cb, out + (size_t)t * BB * HH);
    }
    finalize_kernel<<<(BB * HH + 255) / 256, 256, 0, stream>>>(cb, out);
  }
}